// Round 1
// baseline (5814.448 us; speedup 1.0000x reference)
//
#include <hip/hip_runtime.h>

typedef unsigned short u16;
typedef __attribute__((ext_vector_type(8))) short bfrag;
typedef __attribute__((ext_vector_type(4))) float f32x4;

#define NB   512     // batch
#define NT   256     // time steps
#define NIN  5
#define HE   256     // encoder hidden
#define KE   288     // encoder extended K: 256 h + 5 x + 1 one + 26 pad
#define HD   512     // decoder hidden
#define KD   672     // decoder extended K: 512 h + 5 x + 1 one + 128 z + 26 pad
#define NZ   128
#define NOUTC 123

// ---------------- ws layout (bytes) ----------------
#define OFF_WEXTF   0ull
#define SZ_WEXTF    (1024ull*KE*2ull)
#define OFF_WEXTD   (OFF_WEXTF + SZ_WEXTF)
#define SZ_WEXTD    (2048ull*KD*2ull)
#define OFF_WDEC    (OFF_WEXTD + SZ_WEXTD)
#define SZ_WDEC     (128ull*KD*2ull)
#define OFF_HENC0   (OFF_WDEC + SZ_WDEC)
#define SZ_HENC     ((unsigned long long)NB*KE*2ull)
#define OFF_HENC1   (OFF_HENC0 + SZ_HENC)
#define OFF_CENC    (OFF_HENC1 + SZ_HENC)
#define SZ_CENC     ((unsigned long long)NB*HE*4ull)
#define OFF_HDEC0   (OFF_CENC + SZ_CENC)
#define SZ_HDEC     ((unsigned long long)NB*KD*2ull)
#define OFF_HDEC1   (OFF_HDEC0 + SZ_HDEC)
#define OFF_CDEC    (OFF_HDEC1 + SZ_HDEC)
#define SZ_CDEC     ((unsigned long long)NB*HD*4ull)
#define OFF_HLAT    (OFF_CDEC + SZ_CDEC)
#define SZ_HLAT     ((unsigned long long)NB*512ull*4ull)
#define OFF_ZBUF    (OFF_HLAT + SZ_HLAT)
#define SZ_ZBUF     ((unsigned long long)NB*NZ*4ull)
#define STATE_OFF   OFF_HENC0
#define STATE_BYTES (OFF_ZBUF + SZ_ZBUF - OFF_HENC0)

__device__ __forceinline__ float bf2f(u16 u) {
  union { unsigned int i; float f; } v; v.i = ((unsigned int)u) << 16; return v.f;
}
__device__ __forceinline__ u16 f2bf(float f) {
  union { float f; unsigned int i; } v; v.f = f;
  unsigned int r = v.i + 0x7fffu + ((v.i >> 16) & 1u);
  return (u16)(r >> 16);
}
__device__ __forceinline__ float sigm(float x) { return 1.0f / (1.0f + __expf(-x)); }
__device__ __forceinline__ float tanh_(float x) {
  float a = fabsf(x);
  float e = __expf(-2.0f * a);
  float r = (1.0f - e) / (1.0f + e);
  return x < 0.0f ? -r : r;
}

// One recurrent step. A = [h | x | 1 | (z)] (bf16, KEXT cols per batch row).
// gates[b, g*HU+n] = A[b,:] . Wext[g*HU+n, :]
// Block (bx, by): by < HU/32 -> gate tile (32 batch rows x 32 h-units, all 4 gates)
//                 by == HU/32 -> y-projection + MDN of PREVIOUS h (decoder only)
template<int HU, int KEXT>
__global__ __launch_bounds__(256) void lstm_step(
    const u16* __restrict__ Wext, const u16* __restrict__ Acur,
    u16* __restrict__ Anext, float* __restrict__ cbuf,
    const float* __restrict__ s, int xt,   // s time index to write into Anext x-slot (-1: skip)
    int gate_on,
    const u16* __restrict__ Wdec,          // [128, KEXT] (y path)
    float* __restrict__ out, int yt)       // y time index (-1: skip)
{
  constexpr int KB  = KEXT / 32;
  constexpr int NBY = HU / 32;
  const int tid = threadIdx.x;
  const int w = tid >> 6;
  const int l = tid & 63;
  const int bx = blockIdx.x;
  const int by = blockIdx.y;
  const int lr = l & 15;          // row-in-tile selector
  const int kofs = (l >> 4) * 8;  // k offset within 32-block

  if (by == NBY) {
    // ---------------- y + MDN path ----------------
    if (yt < 0) return;
    __shared__ float ylds[32][129];
    __shared__ float red[32][4];

    const int mloc = (w >> 1) * 16;
    const int arow = bx * 32 + mloc + lr;
    const u16* Aptr = Acur + (size_t)arow * KEXT + kofs;
    const int nb4 = (w & 1) * 64;
    const u16* Bp[4];
    #pragma unroll
    for (int nt = 0; nt < 4; ++nt)
      Bp[nt] = Wdec + (size_t)(nb4 + nt * 16 + lr) * KEXT + kofs;

    f32x4 acc[4];
    #pragma unroll
    for (int nt = 0; nt < 4; ++nt) acc[nt] = f32x4{0.f, 0.f, 0.f, 0.f};

    #pragma unroll 3
    for (int kb = 0; kb < KB; ++kb) {
      bfrag a = *reinterpret_cast<const bfrag*>(Aptr + kb * 32);
      #pragma unroll
      for (int nt = 0; nt < 4; ++nt) {
        bfrag bf = *reinterpret_cast<const bfrag*>(Bp[nt] + kb * 32);
        acc[nt] = __builtin_amdgcn_mfma_f32_16x16x32_bf16(a, bf, acc[nt], 0, 0, 0);
      }
    }
    #pragma unroll
    for (int nt = 0; nt < 4; ++nt)
      #pragma unroll
      for (int j = 0; j < 4; ++j)
        ylds[mloc + (l >> 4) * 4 + j][nb4 + nt * 16 + lr] = acc[nt][j];
    __syncthreads();

    if (tid < 32) {
      float m1 = -1e30f;
      #pragma unroll
      for (int k = 0; k < 20; ++k) m1 = fmaxf(m1, ylds[tid][6 * k]);
      float s1 = 0.f;
      #pragma unroll
      for (int k = 0; k < 20; ++k) s1 += __expf(ylds[tid][6 * k] - m1);
      float p0 = ylds[tid][120], p1 = ylds[tid][121], p2 = ylds[tid][122];
      float mp = fmaxf(p0, fmaxf(p1, p2));
      float sp = __expf(p0 - mp) + __expf(p1 - mp) + __expf(p2 - mp);
      red[tid][0] = m1; red[tid][1] = 1.f / s1; red[tid][2] = mp; red[tid][3] = 1.f / sp;
    }
    __syncthreads();

    {
      int r = tid >> 3, p = tid & 7;
      int b = bx * 32 + r;
      float* orow = out + ((size_t)b * NT + yt) * NOUTC;
      float m1 = red[r][0], i1 = red[r][1], mp = red[r][2], ip = red[r][3];
      #pragma unroll
      for (int cc = 0; cc < 16; ++cc) {
        int c = p * 16 + cc;
        if (c >= NOUTC) break;
        float y = ylds[r][c];
        float v;
        if (c < 120) {
          int rem = c % 6;
          if (rem == 0)      v = __expf(y - m1) * i1;
          else if (rem <= 2) v = y;
          else if (rem <= 4) v = __expf(y);
          else               v = tanh_(y);
        } else {
          v = __expf(y - mp) * ip;
        }
        orow[c] = v;
      }
    }
    return;
  }

  // ---------------- gate path ----------------
  if (gate_on) {
    const int mbase = bx * 32 + (w >> 1) * 16;
    const int nloc  = by * 32 + (w & 1) * 16;
    const int arow  = mbase + lr;
    const u16* Aptr = Acur + (size_t)arow * KEXT + kofs;
    const u16* Bp[4];
    #pragma unroll
    for (int g = 0; g < 4; ++g)
      Bp[g] = Wext + (size_t)(g * HU + nloc + lr) * KEXT + kofs;

    f32x4 acc[4];
    #pragma unroll
    for (int g = 0; g < 4; ++g) acc[g] = f32x4{0.f, 0.f, 0.f, 0.f};

    #pragma unroll 3
    for (int kb = 0; kb < KB; ++kb) {
      bfrag a = *reinterpret_cast<const bfrag*>(Aptr + kb * 32);
      #pragma unroll
      for (int g = 0; g < 4; ++g) {
        bfrag bf = *reinterpret_cast<const bfrag*>(Bp[g] + kb * 32);
        acc[g] = __builtin_amdgcn_mfma_f32_16x16x32_bf16(a, bf, acc[g], 0, 0, 0);
      }
    }

    const int n = nloc + lr;
    #pragma unroll
    for (int j = 0; j < 4; ++j) {
      int b = mbase + (l >> 4) * 4 + j;
      size_t ci = (size_t)b * HU + n;
      float c = cbuf[ci];
      float ii = sigm(acc[0][j]);
      float ff = sigm(acc[1][j]);
      float gg = tanh_(acc[2][j]);
      float oo = sigm(acc[3][j]);
      c = ff * c + ii * gg;
      float h = oo * tanh_(c);
      cbuf[ci] = c;
      Anext[(size_t)b * KEXT + n] = f2bf(h);
    }
  }

  // x-slot writer for next step's A buffer
  if (by == 0 && xt >= 0 && tid < 32 * NIN) {
    int r = tid / NIN, cc = tid % NIN;
    int b = bx * 32 + r;
    Anext[(size_t)b * KEXT + HU + cc] = f2bf(s[((size_t)b * NT + xt) * NIN + cc]);
  }
}

// ---------------- prep kernels ----------------
__global__ void prep_wext_f(const float* __restrict__ Whh, const float* __restrict__ Wih,
                            const float* __restrict__ bi, const float* __restrict__ bh,
                            u16* __restrict__ W) {
  int idx = blockIdx.x * 256 + threadIdx.x;
  if (idx >= 1024 * KE) return;
  int n = idx / KE, k = idx % KE;
  float v = 0.f;
  if (k < 256) v = Whh[n * 256 + k];
  else if (k < 261) v = Wih[n * 5 + (k - 256)];
  else if (k == 261) v = bi[n] + bh[n];
  W[idx] = f2bf(v);
}

__global__ void prep_wext_d(const float* __restrict__ Whh, const float* __restrict__ Wih,
                            const float* __restrict__ bi, const float* __restrict__ bh,
                            u16* __restrict__ W) {
  int idx = blockIdx.x * 256 + threadIdx.x;
  if (idx >= 2048 * KD) return;
  int n = idx / KD, k = idx % KD;
  float v = 0.f;
  if (k < 512) v = Whh[n * 512 + k];
  else if (k < 517) v = Wih[n * 133 + (k - 512)];
  else if (k == 517) v = bi[n] + bh[n];
  else if (k < 646) v = Wih[n * 133 + 5 + (k - 518)];
  W[idx] = f2bf(v);
}

__global__ void prep_wdec(const float* __restrict__ Wd, const float* __restrict__ bd,
                          u16* __restrict__ W) {
  int idx = blockIdx.x * 256 + threadIdx.x;
  if (idx >= 128 * KD) return;
  int n = idx / KD, k = idx % KD;
  float v = 0.f;
  if (n < NOUTC) {
    if (k < 512) v = Wd[n * 512 + k];
    else if (k == 517) v = bd[n];
  }
  W[idx] = f2bf(v);
}

__global__ void prep_state(const float* __restrict__ s,
                           u16* __restrict__ henc0, u16* __restrict__ henc1,
                           u16* __restrict__ hdec0, u16* __restrict__ hdec1) {
  int b = blockIdx.x * 256 + threadIdx.x;
  if (b >= NB) return;
  const u16 one = f2bf(1.0f);
  henc0[(size_t)b * KE + 261] = one;
  henc1[(size_t)b * KE + 261] = one;
  for (int i = 0; i < NIN; ++i)
    henc0[(size_t)b * KE + HE + i] = f2bf(s[((size_t)b * NT + 0) * NIN + i]);
  hdec0[(size_t)b * KD + 517] = one;
  hdec1[(size_t)b * KD + 517] = one;
  hdec0[(size_t)b * KD + HD + 2] = one;   // s0 = [0,0,1,0,0]
}

// single backward LSTM step (h0=c0=0, input x[T-1]) + hf copy into hlat
__global__ void backward_latprep(const float* __restrict__ s, const float* __restrict__ Wih_b,
                                 const float* __restrict__ bih_b, const float* __restrict__ bhh_b,
                                 const u16* __restrict__ henc_final, float* __restrict__ hlat) {
  int idx = blockIdx.x * 256 + threadIdx.x;
  if (idx >= NB * HE) return;
  int b = idx >> 8, n = idx & 255;
  float x[5];
  #pragma unroll
  for (int i = 0; i < 5; ++i) x[i] = s[((size_t)b * NT + (NT - 1)) * NIN + i];
  float g[4];
  #pragma unroll
  for (int gg = 0; gg < 4; ++gg) {
    int row = gg * 256 + n;
    float a = bih_b[row] + bhh_b[row];
    #pragma unroll
    for (int i = 0; i < 5; ++i) a += x[i] * Wih_b[row * 5 + i];
    g[gg] = a;
  }
  float c = sigm(g[0]) * tanh_(g[2]);
  float h = sigm(g[3]) * tanh_(c);
  hlat[(size_t)b * 512 + 256 + n] = h;
  hlat[(size_t)b * 512 + n] = bf2f(henc_final[(size_t)b * KE + n]);
}

__global__ void latentA(const float* __restrict__ hlat,
                        const float* __restrict__ Wsig, const float* __restrict__ bsig,
                        const float* __restrict__ Wmu, const float* __restrict__ bmu,
                        const float* __restrict__ eps,
                        float* __restrict__ outmu, float* __restrict__ outpresig,
                        float* __restrict__ zbuf,
                        u16* __restrict__ hdec0, u16* __restrict__ hdec1) {
  int idx = blockIdx.x * 256 + threadIdx.x;
  if (idx >= NB * NZ) return;
  int b = idx >> 7, zj = idx & 127;
  const float4* hr = (const float4*)(hlat + (size_t)b * 512);
  const float4* ws = (const float4*)(Wsig + (size_t)zj * 512);
  const float4* wm = (const float4*)(Wmu + (size_t)zj * 512);
  float ps = bsig[zj], mu = bmu[zj];
  for (int k = 0; k < 128; ++k) {
    float4 h = hr[k], a = ws[k], m = wm[k];
    ps += h.x * a.x + h.y * a.y + h.z * a.z + h.w * a.w;
    mu += h.x * m.x + h.y * m.y + h.z * m.z + h.w * m.w;
  }
  outmu[(size_t)b * NZ + zj] = mu;
  outpresig[(size_t)b * NZ + zj] = ps;
  float z = mu + __expf(0.5f * ps) * eps[zj];
  zbuf[(size_t)b * NZ + zj] = z;
  u16 zb = f2bf(z);
  hdec0[(size_t)b * KD + 518 + zj] = zb;
  hdec1[(size_t)b * KD + 518 + zj] = zb;
}

__global__ void latentB(const float* __restrict__ zbuf, const float* __restrict__ Wh0,
                        const float* __restrict__ bh0, u16* __restrict__ hdec0) {
  int idx = blockIdx.x * 256 + threadIdx.x;
  if (idx >= NB * HD) return;
  int b = idx >> 9, d = idx & 511;
  float a = bh0[d];
  const float4* zr = (const float4*)(zbuf + (size_t)b * NZ);
  const float4* wr = (const float4*)(Wh0 + (size_t)d * NZ);
  for (int k = 0; k < 32; ++k) {
    float4 z = zr[k], w = wr[k];
    a += z.x * w.x + z.y * w.y + z.z * w.z + z.w * w.w;
  }
  hdec0[(size_t)b * KD + d] = f2bf(tanh_(a));
}

extern "C" void kernel_launch(void* const* d_in, const int* in_sizes, int n_in,
                              void* d_out, int out_size, void* d_ws, size_t ws_size,
                              hipStream_t stream) {
  const float* s       = (const float*)d_in[0];
  const float* eps     = (const float*)d_in[1];
  const float* Wih_f   = (const float*)d_in[2];
  const float* Whh_f   = (const float*)d_in[3];
  const float* bih_f   = (const float*)d_in[4];
  const float* bhh_f   = (const float*)d_in[5];
  const float* Wih_b   = (const float*)d_in[6];
  const float* bih_b   = (const float*)d_in[8];
  const float* bhh_b   = (const float*)d_in[9];
  const float* W_sigma = (const float*)d_in[10];
  const float* b_sigma = (const float*)d_in[11];
  const float* W_mu    = (const float*)d_in[12];
  const float* b_mu    = (const float*)d_in[13];
  const float* W_h0    = (const float*)d_in[14];
  const float* b_h0    = (const float*)d_in[15];
  const float* Wih_d   = (const float*)d_in[16];
  const float* Whh_d   = (const float*)d_in[17];
  const float* bih_d   = (const float*)d_in[18];
  const float* bhh_d   = (const float*)d_in[19];
  const float* W_dec   = (const float*)d_in[20];
  const float* b_dec   = (const float*)d_in[21];

  char* ws = (char*)d_ws;
  u16* WEXTF = (u16*)(ws + OFF_WEXTF);
  u16* WEXTD = (u16*)(ws + OFF_WEXTD);
  u16* WDECX = (u16*)(ws + OFF_WDEC);
  u16* HENC0 = (u16*)(ws + OFF_HENC0);
  u16* HENC1 = (u16*)(ws + OFF_HENC1);
  float* CENC = (float*)(ws + OFF_CENC);
  u16* HDEC0 = (u16*)(ws + OFF_HDEC0);
  u16* HDEC1 = (u16*)(ws + OFF_HDEC1);
  float* CDEC = (float*)(ws + OFF_CDEC);
  float* HLAT = (float*)(ws + OFF_HLAT);
  float* ZBUF = (float*)(ws + OFF_ZBUF);

  float* out = (float*)d_out;
  float* out_mu = out + 16121856;
  float* out_presig = out + 16187392;

  hipMemsetAsync(ws + STATE_OFF, 0, (size_t)STATE_BYTES, stream);

  prep_wext_f<<<(1024 * KE + 255) / 256, 256, 0, stream>>>(Whh_f, Wih_f, bih_f, bhh_f, WEXTF);
  prep_wext_d<<<(2048 * KD + 255) / 256, 256, 0, stream>>>(Whh_d, Wih_d, bih_d, bhh_d, WEXTD);
  prep_wdec<<<(128 * KD + 255) / 256, 256, 0, stream>>>(W_dec, b_dec, WDECX);
  prep_state<<<2, 256, 0, stream>>>(s, HENC0, HENC1, HDEC0, HDEC1);

  // encoder forward LSTM
  for (int t = 0; t < NT; ++t) {
    const u16* cur = (t & 1) ? HENC1 : HENC0;
    u16* nxt = (t & 1) ? HENC0 : HENC1;
    lstm_step<HE, KE><<<dim3(16, 8), 256, 0, stream>>>(
        WEXTF, cur, nxt, CENC, s, (t < NT - 1) ? (t + 1) : -1, 1,
        (const u16*)nullptr, (float*)nullptr, -1);
  }

  backward_latprep<<<(NB * HE + 255) / 256, 256, 0, stream>>>(s, Wih_b, bih_b, bhh_b, HENC0, HLAT);
  latentA<<<(NB * NZ + 255) / 256, 256, 0, stream>>>(HLAT, W_sigma, b_sigma, W_mu, b_mu, eps,
                                                     out_mu, out_presig, ZBUF, HDEC0, HDEC1);
  latentB<<<(NB * HD + 255) / 256, 256, 0, stream>>>(ZBUF, W_h0, b_h0, HDEC0);

  // decoder LSTM; kernel t computes h_t and y_{t-1}(+MDN); t==NT does only y_{NT-1}
  for (int t = 0; t <= NT; ++t) {
    const u16* cur = (t & 1) ? HDEC1 : HDEC0;
    u16* nxt = (t & 1) ? HDEC0 : HDEC1;
    lstm_step<HD, KD><<<dim3(16, 17), 256, 0, stream>>>(
        WEXTD, cur, nxt, CDEC, s, (t < NT) ? t : -1, (t < NT) ? 1 : 0,
        WDECX, out, t - 1);
  }
  (void)in_sizes; (void)n_in; (void)out_size; (void)ws_size; (void)d_in;
}